// Round 4
// baseline (236.830 us; speedup 1.0000x reference)
//
#include <hip/hip_runtime.h>

// J-loss via MFMA: T[b,i,k] = sum_p pred[b,i,p] * onehot(target[b,p]==k)
// j[b] = -sum_{i!=k} log(0.5 + 0.5*(T[b,i,i]/n[b,i] - T[b,i,k]/n[b,k]))
//
// R3 post-mortem: direct A-fragment loads scatter across 16 channel rows
// (576 KB apart) per instruction -> 32 cacheline probes/instr, fragmented HBM.
// R4: global_load_lds(16B) stages [32ch x 256px] tile (1 KB contiguous per
// instr), fragments read from LDS (stride 258 = +2 pad, 4-way alias only).
// Counts still fused via mfma(ONES, B). Grid 4608 = 18 blocks/CU exactly.

#define BB 8
#define CC 32
#define HW 147456                 // 384*384
#define PX_BLK 256                // pixels per block tile
#define NCHUNK (HW / PX_BLK)      // 576
#define STRIDE 258                // tile row stride in floats (8B-aligned rows)

typedef __attribute__((ext_vector_type(8))) short short8;
typedef __attribute__((ext_vector_type(4))) float float4v;
typedef __attribute__((ext_vector_type(4))) unsigned uint4v;

// pack trunc-bf16(lo), trunc-bf16(hi) into one dword: 1 v_perm_b32
__device__ __forceinline__ unsigned pk(float lo, float hi) {
    return __builtin_amdgcn_perm(__float_as_uint(hi), __float_as_uint(lo), 0x07060302u);
}
// packed pair of one-hot bf16 values for classes (ta,tb) vs m
__device__ __forceinline__ unsigned oh2(int ta, int tb, int m) {
    return (ta == m ? 0x3F80u : 0u) | (tb == m ? 0x3F800000u : 0u);
}

__global__ __launch_bounds__(256, 4) void jloss_mfma(
    const float* __restrict__ pred,    // [B][C][HW]
    const int*   __restrict__ target,  // [B][HW]
    float*       __restrict__ T,       // [B][C][C] pre-zeroed
    float*       __restrict__ cnt)     // [B][C]    pre-zeroed
{
    __shared__ float tile[CC * STRIDE];   // 33 KB; reused for reduction

    const int tid  = threadIdx.x;
    const int w    = tid >> 6;         // wave 0..3
    const int l    = tid & 63;
    const int quad = l >> 4;
    const int m    = l & 15;
    const int blk  = blockIdx.x;
    const int b    = blk / NCHUNK;
    const int chunk= blk % NCHUNK;

    const long px0 = (long)chunk * PX_BLK;
    const float* predb = pred + (long)b * CC * HW;
    const int*   tgtb  = target + (long)b * HW;

    // ---- stage: wave w copies channel rows w*8 .. w*8+7, 1 KB each, async ----
    #pragma unroll
    for (int r = 0; r < 8; ++r) {
        const int c = w * 8 + r;
        const float* gp = predb + (long)c * HW + px0 + l * 4;   // lane: 16B contiguous
        __builtin_amdgcn_global_load_lds(
            (const __attribute__((address_space(1))) void*)gp,
            (__attribute__((address_space(3))) void*)&tile[c * STRIDE + l * 4],
            16, 0, 0);
    }
    __syncthreads();   // drains vmcnt before LDS reads

    // ---- compute: wave w owns K-steps {2w, 2w+1} (64 px) ----
    float4v acc00 = {0,0,0,0}, acc01 = {0,0,0,0};
    float4v acc10 = {0,0,0,0}, acc11 = {0,0,0,0};
    float4v accc0 = {0,0,0,0}, accc1 = {0,0,0,0};   // counts: ones . B
    const short8 ONES = {0x3F80,0x3F80,0x3F80,0x3F80,0x3F80,0x3F80,0x3F80,0x3F80};

    #pragma unroll
    for (int kk = 0; kk < 2; ++kk) {
        const int ks   = w * 2 + kk;
        const int base = ks * 32 + quad * 8;
        const float2* r0 = (const float2*)&tile[m * STRIDE + base];          // ch m
        const float2* r1 = (const float2*)&tile[(m + 16) * STRIDE + base];   // ch m+16
        const float2 x0 = r0[0], x1 = r0[1], x2 = r0[2], x3 = r0[3];
        const float2 y0 = r1[0], y1 = r1[1], y2 = r1[2], y3 = r1[3];
        const int4 t0 = *(const int4*)(tgtb + px0 + base);
        const int4 t1 = *(const int4*)(tgtb + px0 + base + 4);

        union { short8 s; uint4v u; } A0, A1, B0, B1;
        A0.u[0] = pk(x0.x, x0.y); A0.u[1] = pk(x1.x, x1.y);
        A0.u[2] = pk(x2.x, x2.y); A0.u[3] = pk(x3.x, x3.y);
        A1.u[0] = pk(y0.x, y0.y); A1.u[1] = pk(y1.x, y1.y);
        A1.u[2] = pk(y2.x, y2.y); A1.u[3] = pk(y3.x, y3.y);
        B0.u[0] = oh2(t0.x, t0.y, m);      B0.u[1] = oh2(t0.z, t0.w, m);
        B0.u[2] = oh2(t1.x, t1.y, m);      B0.u[3] = oh2(t1.z, t1.w, m);
        const int m16 = m + 16;
        B1.u[0] = oh2(t0.x, t0.y, m16);    B1.u[1] = oh2(t0.z, t0.w, m16);
        B1.u[2] = oh2(t1.x, t1.y, m16);    B1.u[3] = oh2(t1.z, t1.w, m16);

        acc00 = __builtin_amdgcn_mfma_f32_16x16x32_bf16(A0.s, B0.s, acc00, 0, 0, 0);
        acc01 = __builtin_amdgcn_mfma_f32_16x16x32_bf16(A0.s, B1.s, acc01, 0, 0, 0);
        acc10 = __builtin_amdgcn_mfma_f32_16x16x32_bf16(A1.s, B0.s, acc10, 0, 0, 0);
        acc11 = __builtin_amdgcn_mfma_f32_16x16x32_bf16(A1.s, B1.s, acc11, 0, 0, 0);
        accc0 = __builtin_amdgcn_mfma_f32_16x16x32_bf16(ONES, B0.s, accc0, 0, 0, 0);
        accc1 = __builtin_amdgcn_mfma_f32_16x16x32_bf16(ONES, B1.s, accc1, 0, 0, 0);
    }
    __syncthreads();   // all tile reads done; safe to reuse tile as reduce buffer

    // ---- cross-wave reduce (tile reused), then one global atomic per entry ----
    float (*red)[CC][CC] = (float (*)[CC][CC])tile;   // [4][32][32] = 16 KB
    float* redc = tile + 4 * CC * CC;                 // [4][32]
    #pragma unroll
    for (int r = 0; r < 4; ++r) {      // C layout: row=quad*4+r, col=m (m89-verified)
        red[w][quad*4 + r     ][m     ] = acc00[r];
        red[w][quad*4 + r     ][m + 16] = acc01[r];
        red[w][quad*4 + r + 16][m     ] = acc10[r];
        red[w][quad*4 + r + 16][m + 16] = acc11[r];
    }
    if (quad == 0) {                   // counts: every row of accc is count[col]
        redc[w * CC + m]      = accc0[0];
        redc[w * CC + m + 16] = accc1[0];
    }
    __syncthreads();

    float* Tb = T + (long)b * CC * CC;
    const float* rp = &red[0][0][0];
    for (int j = tid; j < CC * CC; j += 256) {
        const float s = rp[j] + rp[1024 + j] + rp[2048 + j] + rp[3072 + j];
        atomicAdd(&Tb[j], s);
    }
    if (tid < CC)
        atomicAdd(&cnt[b * CC + tid],
                  redc[tid] + redc[CC + tid] + redc[2*CC + tid] + redc[3*CC + tid]);
}

__global__ __launch_bounds__(256) void jloss_final(
    const float* __restrict__ T,
    const float* __restrict__ cnt,
    float*       __restrict__ out)
{
    const int b   = blockIdx.x;
    const int tid = threadIdx.x;
    __shared__ float diag_s[CC];
    __shared__ float inv_n[CC];
    __shared__ float wsum[4];

    const float* Tb = T + (long)b * CC * CC;
    const float* cb = cnt + b * CC;

    if (tid < CC) {
        const float inv = 1.0f / cb[tid];
        inv_n[tid]  = inv;
        diag_s[tid] = Tb[tid * CC + tid] * inv;
    }
    __syncthreads();

    float sum = 0.0f;
    for (int idx = tid; idx < CC * CC; idx += 256) {
        const int i = idx >> 5;
        const int k = idx & 31;
        if (i != k) {
            const float S = Tb[idx] * inv_n[k];
            sum += logf(0.5f + 0.5f * (diag_s[i] - S));
        }
    }
    #pragma unroll
    for (int off = 32; off > 0; off >>= 1) sum += __shfl_down(sum, off, 64);
    if ((tid & 63) == 0) wsum[tid >> 6] = sum;
    __syncthreads();
    if (tid == 0) out[b] = -(wsum[0] + wsum[1] + wsum[2] + wsum[3]);
}

extern "C" void kernel_launch(void* const* d_in, const int* in_sizes, int n_in,
                              void* d_out, int out_size, void* d_ws, size_t ws_size,
                              hipStream_t stream) {
    const float* pred   = (const float*)d_in[0];
    const int*   target = (const int*)d_in[1];
    float* out = (float*)d_out;

    float* T   = (float*)d_ws;                       // 8*32*32 floats
    float* cnt = (float*)d_ws + BB * CC * CC;        // 8*32 floats

    hipMemsetAsync(d_ws, 0, (BB * CC * CC + BB * CC) * sizeof(float), stream);

    jloss_mfma <<<BB * NCHUNK, 256, 0, stream>>>(pred, target, T, cnt);
    jloss_final<<<BB, 256, 0, stream>>>(T, cnt, out);
}